// Round 2
// baseline (470.318 us; speedup 1.0000x reference)
//
#include <hip/hip_runtime.h>
#include <hip/hip_bf16.h>
#include <cmath>

#define TT 1024
#define HH 1024
#define FF 768
#define EE 32

typedef __bf16 bf16;
typedef __bf16 v8bf __attribute__((ext_vector_type(8)));
typedef float  v4f  __attribute__((ext_vector_type(4)));

static __device__ __forceinline__ v4f mfma16(v8bf a, v8bf b, v4f c) {
    return __builtin_amdgcn_mfma_f32_16x16x32_bf16(a, b, c, 0, 0, 0);
}

// ---------------------------------------------------------------- router
// 1 wave per token. Double-precision dot so top-k selection matches the
// high-precision reference except at ~1e-15 ties.
__global__ __launch_bounds__(64) void router_k(
    const float* __restrict__ x, const float* __restrict__ gw,
    bf16* __restrict__ xbf, int* __restrict__ tk_id, float* __restrict__ tk_w)
{
    int t = blockIdx.x, lane = threadIdx.x;
    float xr[16];
#pragma unroll
    for (int i = 0; i < 16; ++i) xr[i] = x[t * HH + i * 64 + lane];
#pragma unroll
    for (int i = 0; i < 16; ++i) xbf[t * HH + i * 64 + lane] = (bf16)xr[i];

    double acc[EE];
#pragma unroll
    for (int e = 0; e < EE; ++e) {
        double a = 0.0;
#pragma unroll
        for (int i = 0; i < 16; ++i)
            a += (double)xr[i] * (double)gw[e * HH + i * 64 + lane];
        acc[e] = a;
    }
#pragma unroll
    for (int m = 1; m < 64; m <<= 1) {
#pragma unroll
        for (int e = 0; e < EE; ++e) acc[e] += __shfl_xor(acc[e], m, 64);
    }
    if (lane == 0) {
        double mx = acc[0];
#pragma unroll
        for (int e = 1; e < EE; ++e) mx = fmax(mx, acc[e]);
        double p[EE];
        double s = 0.0;
#pragma unroll
        for (int e = 0; e < EE; ++e) { p[e] = exp(acc[e] - mx); s += p[e]; }
        int ids[4]; double w[4]; double ws = 0.0;
        for (int k = 0; k < 4; ++k) {
            int best = 0; double bv = -1.0;
            for (int e = 0; e < EE; ++e)
                if (p[e] > bv) { bv = p[e]; best = e; }
            ids[k] = best; w[k] = bv; ws += bv; p[best] = -2.0;
        }
        for (int k = 0; k < 4; ++k) {
            tk_id[t * 4 + k] = ids[k];
            tk_w[t * 4 + k] = (float)(w[k] / ws);
        }
    }
}

// ---------------------------------------------------------------- scatter
// Single block: LDS count -> scan -> compact per-expert (token*4+k, weight).
__global__ __launch_bounds__(1024) void scatter_k(
    const int* __restrict__ tk_id, const float* __restrict__ tk_w,
    int* __restrict__ cnt, int* __restrict__ offs,
    int* __restrict__ list, float* __restrict__ wlist)
{
    __shared__ int c_s[EE], o_s[EE], cur_s[EE];
    int tid = threadIdx.x;
    if (tid < EE) { c_s[tid] = 0; cur_s[tid] = 0; }
    __syncthreads();
    int ids[4]; float w[4];
#pragma unroll
    for (int k = 0; k < 4; ++k) { ids[k] = tk_id[tid * 4 + k]; w[k] = tk_w[tid * 4 + k]; }
#pragma unroll
    for (int k = 0; k < 4; ++k) atomicAdd(&c_s[ids[k]], 1);
    __syncthreads();
    if (tid == 0) {
        int a = 0;
        for (int e = 0; e < EE; ++e) { o_s[e] = a; a += c_s[e]; }
    }
    __syncthreads();
#pragma unroll
    for (int k = 0; k < 4; ++k) {
        int e = ids[k];
        int pos = atomicAdd(&cur_s[e], 1);
        int idx = o_s[e] + pos;
        list[idx] = tid * 4 + k;
        wlist[idx] = w[k];
    }
    if (tid < EE) { cnt[tid] = c_s[tid]; offs[tid] = o_s[tid]; }
    if (tid >= 1024 - 64) {                 // pad tail so tile reads stay in-bounds
        list[4096 + (tid - 960)] = 0;
        wlist[4096 + (tid - 960)] = 0.f;
    }
}

// ---------------------------------------------------------------- gemm1 + silu
// grid (12 f-blocks, 32 experts), 256 threads. Tile 64 tokens x (64 g + 64 u),
// K=1024 step 64. Each wave owns matching g/u columns so act is register-local.
__global__ __launch_bounds__(256) void gemm1_k(
    const bf16* __restrict__ xbf, const float* __restrict__ w1,
    const int* __restrict__ cnt, const int* __restrict__ offs,
    const int* __restrict__ list, bf16* __restrict__ act)
{
    int e = blockIdx.y, fb = blockIdx.x;
    int n = cnt[e];
    if (n == 0) return;
    int base = offs[e];

    __shared__ bf16 As[64][72];
    __shared__ bf16 Bs[128][72];

    int tid = threadIdx.x;
    int wid = tid >> 6, lane = tid & 63;
    int wr = wid >> 1, wc = wid & 1;
    int lrow = lane & 15, lk = (lane >> 4) * 8;
    const float* w1e = w1 + (size_t)e * 1536 * HH;

    int nm = (n + 63) >> 6;
    for (int mt = 0; mt < nm; ++mt) {
        v4f accg[2][2], accu[2][2];
#pragma unroll
        for (int m = 0; m < 2; ++m)
#pragma unroll
            for (int nf = 0; nf < 2; ++nf) { accg[m][nf] = (v4f)0.f; accu[m][nf] = (v4f)0.f; }

        for (int k0 = 0; k0 < HH; k0 += 64) {
            // stage A (gathered token rows, bf16 direct)
#pragma unroll
            for (int it = 0; it < 2; ++it) {
                int idx = it * 256 + tid;
                int r = idx >> 3, oct = idx & 7;
                int code = list[base + mt * 64 + r];
                int tk = code >> 2;
                *(v8bf*)&As[r][oct * 8] =
                    *(const v8bf*)(xbf + (size_t)tk * HH + k0 + oct * 8);
            }
            // stage B (w1 fp32 -> bf16): rows 0..63 = g, 64..127 = u
#pragma unroll
            for (int it = 0; it < 8; ++it) {
                int r = it * 16 + (tid >> 4);
                int q = tid & 15;
                int grow = (r < 64) ? (fb * 64 + r) : (768 + fb * 64 + (r - 64));
                float4 v = *(const float4*)(w1e + (size_t)grow * HH + k0 + q * 4);
                bf16* dst = &Bs[r][q * 4];
                dst[0] = (bf16)v.x; dst[1] = (bf16)v.y;
                dst[2] = (bf16)v.z; dst[3] = (bf16)v.w;
            }
            __syncthreads();
#pragma unroll
            for (int ks = 0; ks < 2; ++ks) {
                int kk = ks * 32 + lk;
                v8bf a0  = *(const v8bf*)&As[wr * 32 + lrow][kk];
                v8bf a1  = *(const v8bf*)&As[wr * 32 + 16 + lrow][kk];
                v8bf bg0 = *(const v8bf*)&Bs[wc * 32 + lrow][kk];
                v8bf bg1 = *(const v8bf*)&Bs[wc * 32 + 16 + lrow][kk];
                v8bf bu0 = *(const v8bf*)&Bs[64 + wc * 32 + lrow][kk];
                v8bf bu1 = *(const v8bf*)&Bs[64 + wc * 32 + 16 + lrow][kk];
                accg[0][0] = mfma16(a0, bg0, accg[0][0]);
                accg[0][1] = mfma16(a0, bg1, accg[0][1]);
                accg[1][0] = mfma16(a1, bg0, accg[1][0]);
                accg[1][1] = mfma16(a1, bg1, accg[1][1]);
                accu[0][0] = mfma16(a0, bu0, accu[0][0]);
                accu[0][1] = mfma16(a0, bu1, accu[0][1]);
                accu[1][0] = mfma16(a1, bu0, accu[1][0]);
                accu[1][1] = mfma16(a1, bu1, accu[1][1]);
            }
            __syncthreads();
        }
        // epilogue: act = silu(g) * u, masked store, compact layout
        int rb = wr * 32 + (lane >> 4) * 4;
#pragma unroll
        for (int m = 0; m < 2; ++m)
#pragma unroll
            for (int nf = 0; nf < 2; ++nf)
#pragma unroll
                for (int j = 0; j < 4; ++j) {
                    int r = mt * 64 + rb + m * 16 + j;
                    if (r < n) {
                        float g = accg[m][nf][j], u = accu[m][nf][j];
                        float a = g / (1.f + __expf(-g)) * u;
                        act[(size_t)(base + r) * FF + fb * 64 + wc * 32 + nf * 16 + lrow] = (bf16)a;
                    }
                }
    }
}

// ---------------------------------------------------------------- gemm2
// grid (16 h-blocks, 32 experts). Tile 64 slots x 64 h, K=768 step 64.
// Scales rows by routing weight and writes per-slot fp32 rows (no atomics).
__global__ __launch_bounds__(256) void gemm2_k(
    const bf16* __restrict__ act, const float* __restrict__ w2,
    const int* __restrict__ cnt, const int* __restrict__ offs,
    const int* __restrict__ list, const float* __restrict__ wlist,
    float* __restrict__ ybuf)
{
    int e = blockIdx.y, hb = blockIdx.x;
    int n = cnt[e];
    if (n == 0) return;
    int base = offs[e];

    __shared__ bf16 As[64][72];
    __shared__ bf16 Bs[64][72];

    int tid = threadIdx.x;
    int wid = tid >> 6, lane = tid & 63;
    int wr = wid >> 1, wc = wid & 1;
    int lrow = lane & 15, lk = (lane >> 4) * 8;
    const float* w2e = w2 + (size_t)e * HH * FF;

    int nm = (n + 63) >> 6;
    for (int mt = 0; mt < nm; ++mt) {
        v4f acc[2][2];
#pragma unroll
        for (int m = 0; m < 2; ++m)
#pragma unroll
            for (int nf = 0; nf < 2; ++nf) acc[m][nf] = (v4f)0.f;

        for (int k0 = 0; k0 < FF; k0 += 64) {
            // stage A (compact act rows, bf16)
#pragma unroll
            for (int it = 0; it < 2; ++it) {
                int idx = it * 256 + tid;
                int r = idx >> 3, oct = idx & 7;
                *(v8bf*)&As[r][oct * 8] =
                    *(const v8bf*)(act + (size_t)(base + mt * 64 + r) * FF + k0 + oct * 8);
            }
            // stage B (w2 fp32 -> bf16), rows = h
#pragma unroll
            for (int it = 0; it < 4; ++it) {
                int r = it * 16 + (tid >> 4);
                int q = tid & 15;
                float4 v = *(const float4*)(w2e + (size_t)(hb * 64 + r) * FF + k0 + q * 4);
                bf16* dst = &Bs[r][q * 4];
                dst[0] = (bf16)v.x; dst[1] = (bf16)v.y;
                dst[2] = (bf16)v.z; dst[3] = (bf16)v.w;
            }
            __syncthreads();
#pragma unroll
            for (int ks = 0; ks < 2; ++ks) {
                int kk = ks * 32 + lk;
                v8bf a0 = *(const v8bf*)&As[wr * 32 + lrow][kk];
                v8bf a1 = *(const v8bf*)&As[wr * 32 + 16 + lrow][kk];
                v8bf b0 = *(const v8bf*)&Bs[wc * 32 + lrow][kk];
                v8bf b1 = *(const v8bf*)&Bs[wc * 32 + 16 + lrow][kk];
                acc[0][0] = mfma16(a0, b0, acc[0][0]);
                acc[0][1] = mfma16(a0, b1, acc[0][1]);
                acc[1][0] = mfma16(a1, b0, acc[1][0]);
                acc[1][1] = mfma16(a1, b1, acc[1][1]);
            }
            __syncthreads();
        }
        int rb = wr * 32 + (lane >> 4) * 4;
#pragma unroll
        for (int m = 0; m < 2; ++m)
#pragma unroll
            for (int j = 0; j < 4; ++j) {
                int r = mt * 64 + rb + m * 16 + j;
                if (r < n) {
                    int code = list[base + r];
                    float w = wlist[base + r];
#pragma unroll
                    for (int nf = 0; nf < 2; ++nf) {
                        int col = wc * 32 + nf * 16 + lrow;
                        ybuf[(size_t)code * HH + hb * 64 + col] = acc[m][nf][j] * w;
                    }
                }
            }
    }
}

// ---------------------------------------------------------------- combine
__global__ __launch_bounds__(256) void combine_k(
    const float* __restrict__ ybuf, float* __restrict__ out)
{
    int idx = blockIdx.x * 256 + threadIdx.x;   // float4 index
    int t = idx >> 8, c = idx & 255;
    const float4* yb = (const float4*)ybuf;
    float4 a = yb[(size_t)(t * 4 + 0) * 256 + c];
    float4 b = yb[(size_t)(t * 4 + 1) * 256 + c];
    float4 d = yb[(size_t)(t * 4 + 2) * 256 + c];
    float4 e = yb[(size_t)(t * 4 + 3) * 256 + c];
    float4 s;
    s.x = a.x + b.x + d.x + e.x;
    s.y = a.y + b.y + d.y + e.y;
    s.z = a.z + b.z + d.z + e.z;
    s.w = a.w + b.w + d.w + e.w;
    ((float4*)out)[(size_t)t * 256 + c] = s;
}

// ---------------------------------------------------------------- launch
extern "C" void kernel_launch(void* const* d_in, const int* in_sizes, int n_in,
                              void* d_out, int out_size, void* d_ws, size_t ws_size,
                              hipStream_t stream)
{
    const float* x  = (const float*)d_in[0];
    const float* gw = (const float*)d_in[1];
    const float* w1 = (const float*)d_in[2];
    const float* w2 = (const float*)d_in[3];
    float* out = (float*)d_out;

    char* ws = (char*)d_ws;
    size_t off = 0;
    auto alloc = [&](size_t bytes) {
        void* p = ws + off;
        off = (off + bytes + 255) & ~(size_t)255;
        return p;
    };
    bf16*  xbf   = (bf16*) alloc((size_t)TT * HH * 2);
    int*   tk_id = (int*)  alloc(4096 * 4);
    float* tk_w  = (float*)alloc(4096 * 4);
    int*   cnt   = (int*)  alloc(EE * 4);
    int*   offs  = (int*)  alloc(EE * 4);
    int*   list  = (int*)  alloc(4160 * 4);
    float* wlist = (float*)alloc(4160 * 4);
    bf16*  act   = (bf16*) alloc((size_t)4160 * FF * 2);
    float* ybuf  = (float*)alloc((size_t)4096 * HH * 4);

    router_k<<<TT, 64, 0, stream>>>(x, gw, xbf, tk_id, tk_w);
    scatter_k<<<1, 1024, 0, stream>>>(tk_id, tk_w, cnt, offs, list, wlist);
    gemm1_k<<<dim3(12, EE), 256, 0, stream>>>(xbf, w1, cnt, offs, list, act);
    gemm2_k<<<dim3(16, EE), 256, 0, stream>>>(act, w2, cnt, offs, list, wlist, ybuf);
    combine_k<<<1024, 256, 0, stream>>>(ybuf, out);
}